// Round 6
// baseline (900.655 us; speedup 1.0000x reference)
//
#include <hip/hip_runtime.h>
#include <hip/hip_bf16.h>
#include <math.h>

#define LN_EPS 1e-5f
#define EPSA 1e-8f
#define SCALE 0.0625f   // 256^-0.5

typedef __attribute__((ext_vector_type(8))) short short8;
typedef __attribute__((ext_vector_type(4))) float f32x4;

__device__ inline unsigned short f2bf(float f) {
    union { float f; unsigned int u; } v; v.f = f;
    unsigned int r = v.u + 0x7fffu + ((v.u >> 16) & 1u);   // RNE
    return (unsigned short)(r >> 16);
}
__device__ inline float bf2f(unsigned short h) {
    union { unsigned int u; float f; } v; v.u = ((unsigned int)h) << 16;
    return v.f;
}
__device__ inline void bf2x(unsigned int u, float& a, float& b) {
    union { unsigned int i; float f; } lo, hi;
    lo.i = u << 16; hi.i = u & 0xffff0000u;
    a = lo.f; b = hi.f;
}
__device__ inline float sigmoidf_(float x) { return 1.0f / (1.0f + expf(-x)); }

// ---------- K1: xn = LN(x) stored as bf16 hi+lo (no k/v materialization) ----------
// block = 256 thr, 64 rows; lane group of 4 (lk) per row slice.
__global__ __launch_bounds__(256) void xn_pass(const float* __restrict__ x,
                                               const float* __restrict__ nx_g,
                                               const float* __restrict__ nx_b,
                                               unsigned short* __restrict__ xnh,
                                               unsigned short* __restrict__ xnl) {
    __shared__ float gb[512];      // nx_g | nx_b
    const int t = threadIdx.x;
    const int l = t & 63, w = t >> 6;
    const int lr = l & 15, lk = l >> 4;
    const int row = blockIdx.x * 64 + w*16 + lr;

    float4 xa[8], xb[8];
    const float* xbase = x + (size_t)row*256 + lk*8;
    #pragma unroll
    for (int ks = 0; ks < 8; ++ks) {
        xa[ks] = *(const float4*)(xbase + ks*32);
        xb[ks] = *(const float4*)(xbase + ks*32 + 4);
    }
    gb[t] = nx_g[t]; gb[t+256] = nx_b[t];

    float s = 0.f, s2 = 0.f;
    #pragma unroll
    for (int ks = 0; ks < 8; ++ks) {
        s  += xa[ks].x + xa[ks].y + xa[ks].z + xa[ks].w
            + xb[ks].x + xb[ks].y + xb[ks].z + xb[ks].w;
        s2 += xa[ks].x*xa[ks].x + xa[ks].y*xa[ks].y + xa[ks].z*xa[ks].z + xa[ks].w*xa[ks].w
            + xb[ks].x*xb[ks].x + xb[ks].y*xb[ks].y + xb[ks].z*xb[ks].z + xb[ks].w*xb[ks].w;
    }
    s  += __shfl_xor(s, 16);  s2 += __shfl_xor(s2, 16);
    s  += __shfl_xor(s, 32);  s2 += __shfl_xor(s2, 32);
    float m = s * (1.0f/256.0f);
    float var = s2 * (1.0f/256.0f) - m*m;
    float rstd = rsqrtf(var + LN_EPS);
    __syncthreads();   // gb ready

    #pragma unroll
    for (int ks = 0; ks < 8; ++ks) {
        int c = ks*32 + lk*8;
        float4 g0 = *(const float4*)&gb[c],     g1 = *(const float4*)&gb[c+4];
        float4 b0 = *(const float4*)&gb[256+c], b1 = *(const float4*)&gb[256+c+4];
        float e[8];
        e[0] = (xa[ks].x - m)*rstd*g0.x + b0.x;
        e[1] = (xa[ks].y - m)*rstd*g0.y + b0.y;
        e[2] = (xa[ks].z - m)*rstd*g0.z + b0.z;
        e[3] = (xa[ks].w - m)*rstd*g0.w + b0.w;
        e[4] = (xb[ks].x - m)*rstd*g1.x + b1.x;
        e[5] = (xb[ks].y - m)*rstd*g1.y + b1.y;
        e[6] = (xb[ks].z - m)*rstd*g1.z + b1.z;
        e[7] = (xb[ks].w - m)*rstd*g1.w + b1.w;
        short8 h, lo;
        #pragma unroll
        for (int j = 0; j < 8; ++j) {
            unsigned short hh = f2bf(e[j]);
            h[j]  = (short)hh;
            lo[j] = (short)f2bf(e[j] - bf2f(hh));
        }
        *(short8*)(xnh + (size_t)row*256 + c) = h;
        *(short8*)(xnl + (size_t)row*256 + c) = lo;
    }
}

// ---------- K2: slots init ----------
__global__ __launch_bounds__(256) void slots_init(const float* __restrict__ noise,
                                                  const float* __restrict__ mu,
                                                  const float* __restrict__ logsigma,
                                                  float* __restrict__ slots) {
    int i = blockIdx.x * 256 + threadIdx.x;   // 65536
    int d = i & 255;
    slots[i] = mu[d] + expf(logsigma[d]) * noise[i];
}

// ---------- K3: LN(slots) -> q = @Wq^T -> qk = q@Wk, hi/lo -> qkb[b][16][256] ----------
__global__ __launch_bounds__(256) void qkproj(const float* __restrict__ slots,
                                              const float* __restrict__ ns_g,
                                              const float* __restrict__ ns_b,
                                              const float* __restrict__ Wq,
                                              const float* __restrict__ Wk,
                                              unsigned short* __restrict__ qkb) {
    int row = blockIdx.x, t = threadIdx.x;   // row = b*8 + s
    int b = row >> 3, s8 = row & 7;
    __shared__ float sn[256], qs[256];
    __shared__ float red[8];
    float v = slots[row*256 + t];
    float s = v, s2 = v*v;
    for (int off = 32; off > 0; off >>= 1) {
        s  += __shfl_down(s, off);
        s2 += __shfl_down(s2, off);
    }
    if ((t & 63) == 0) { red[t>>6] = s; red[4 + (t>>6)] = s2; }
    __syncthreads();
    float S  = red[0]+red[1]+red[2]+red[3];
    float S2 = red[4]+red[5]+red[6]+red[7];
    float m = S * (1.0f/256.0f);
    float var = S2 * (1.0f/256.0f) - m*m;
    float rs = rsqrtf(var + LN_EPS);
    sn[t] = (v - m) * rs * ns_g[t] + ns_b[t];
    __syncthreads();
    // q[t] = Wq[t,:] . sn
    float qacc = 0.0f;
    const float4* wrow = (const float4*)(Wq + (size_t)t*256);
    #pragma unroll 8
    for (int i = 0; i < 64; ++i) {
        float4 w = wrow[i];
        qacc += w.x*sn[4*i] + w.y*sn[4*i+1] + w.z*sn[4*i+2] + w.w*sn[4*i+3];
    }
    qs[t] = qacc;
    __syncthreads();
    // qk[t] = sum_d qs[d] * Wk[d, t]   (coalesced across t per d-step)
    float acc = 0.0f;
    #pragma unroll 4
    for (int d = 0; d < 256; ++d)
        acc += qs[d] * Wk[(size_t)d*256 + t];
    unsigned short hh = f2bf(acc);
    unsigned short ll = f2bf(acc - bf2f(hh));
    qkb[((size_t)(b*16 + s8))*256 + t]     = hh;
    qkb[((size_t)(b*16 + 8 + s8))*256 + t] = ll;
}

// ---------- K4: MFMA logits (hi/lo exact) + softmax + attn out + VALU ax ----------
// grid (b, chunk of 256 n) = 32*16; 4 waves.
__global__ __launch_bounds__(256) void attn_fused(const unsigned short* __restrict__ xnh,
                                                  const unsigned short* __restrict__ xnl,
                                                  const unsigned short* __restrict__ qkb,
                                                  float* __restrict__ attn_out,
                                                  float* __restrict__ partial) {
    __shared__ float asf[8*256];    // f32 attn [slot][n_local]
    const int b = blockIdx.x >> 4, c = blockIdx.x & 15;
    const int t = threadIdx.x, l = t & 63, w = t >> 6;
    const int lr = l & 15, lk = l >> 4;
    const int n0 = c * 256;

    // qk fragments: B-cols 0-7 = qk_hi rows, 8-15 = qk_lo rows
    short8 qf[8];
    #pragma unroll
    for (int ks = 0; ks < 8; ++ks)
        qf[ks] = *(const short8*)(qkb + ((size_t)(b*16 + lr))*256 + ks*32 + lk*8);

    // logits: A = xn_hi rows (acc1) and xn_lo rows (acc2); wave w owns n-sub w*64..+63
    f32x4 acc1[4], acc2[4];
    #pragma unroll
    for (int nf = 0; nf < 4; ++nf) {
        acc1[nf] = (f32x4){0.f,0.f,0.f,0.f};
        acc2[nf] = (f32x4){0.f,0.f,0.f,0.f};
    }
    #pragma unroll
    for (int ks = 0; ks < 8; ++ks) {
        #pragma unroll
        for (int nf = 0; nf < 4; ++nf) {
            size_t rowoff = ((size_t)(b*4096 + n0 + w*64 + nf*16 + lr))*256 + ks*32 + lk*8;
            short8 ah = *(const short8*)(xnh + rowoff);
            acc1[nf] = __builtin_amdgcn_mfma_f32_16x16x32_bf16(ah, qf[ks], acc1[nf], 0, 0, 0);
            short8 al = *(const short8*)(xnl + rowoff);
            acc2[nf] = __builtin_amdgcn_mfma_f32_16x16x32_bf16(al, qf[ks], acc2[nf], 0, 0, 0);
        }
    }

    // combine hi/lo cols (s, s+8) and hi/lo A-passes; softmax over slots (lane bits 0-2)
    const float renorm = 1.0f / (1.0f + 8.0f*EPSA);
    #pragma unroll
    for (int nf = 0; nf < 4; ++nf) {
        #pragma unroll
        for (int jj = 0; jj < 4; ++jj) {
            float c1 = acc1[nf][jj];
            c1 += __shfl_xor(c1, 8);
            float c2 = acc2[nf][jj];
            c2 += __shfl_xor(c2, 8);
            float lg = (c1 + c2) * SCALE;
            float mx = lg;
            mx = fmaxf(mx, __shfl_xor(mx, 1));
            mx = fmaxf(mx, __shfl_xor(mx, 2));
            mx = fmaxf(mx, __shfl_xor(mx, 4));
            float e = expf(lg - mx);
            float ss = e;
            ss += __shfl_xor(ss, 1);
            ss += __shfl_xor(ss, 2);
            ss += __shfl_xor(ss, 4);
            acc1[nf][jj] = (e / ss + EPSA) * renorm;
        }
    }

    if (lr < 8) {
        #pragma unroll
        for (int nf = 0; nf < 4; ++nf) {
            int nl = w*64 + nf*16 + lk*4;
            float4 fa = {acc1[nf][0], acc1[nf][1], acc1[nf][2], acc1[nf][3]};
            *(float4*)&asf[lr*256 + nl] = fa;
        }
    }
    __syncthreads();

    // coalesced attn output
    {
        int slot = t >> 5, nn = (t & 31) * 8;
        float4 f0 = *(float4*)&asf[slot*256 + nn];
        float4 f1 = *(float4*)&asf[slot*256 + nn + 4];
        float* dstp = attn_out + ((size_t)(b*8 + slot))*4096 + n0 + nn;
        *(float4*)dstp = f0;
        *(float4*)(dstp + 4) = f1;
    }

    // ax[s,i] = sum_n attn[s,n]*xn[n,i]  (VALU f32; wave w covers s = 2w, 2w+1)
    {
        int ig = l & 31, no = l >> 5;
        float pa0[8] = {0,0,0,0,0,0,0,0};
        float pa1[8] = {0,0,0,0,0,0,0,0};
        const unsigned short* hB = xnh + ((size_t)(b*4096 + n0))*256 + ig*8;
        const unsigned short* lB = xnl + ((size_t)(b*4096 + n0))*256 + ig*8;
        const float* a0row = &asf[(2*w)*256];
        const float* a1row = &asf[(2*w+1)*256];
        for (int n = no; n < 256; n += 2) {
            uint4 uh = *(const uint4*)(hB + (size_t)n*256);
            uint4 ul = *(const uint4*)(lB + (size_t)n*256);
            float fh[8], fl[8];
            bf2x(uh.x, fh[0], fh[1]); bf2x(uh.y, fh[2], fh[3]);
            bf2x(uh.z, fh[4], fh[5]); bf2x(uh.w, fh[6], fh[7]);
            bf2x(ul.x, fl[0], fl[1]); bf2x(ul.y, fl[2], fl[3]);
            bf2x(ul.z, fl[4], fl[5]); bf2x(ul.w, fl[6], fl[7]);
            float a0 = a0row[n], a1 = a1row[n];
            #pragma unroll
            for (int j = 0; j < 8; ++j) {
                float fs = fh[j] + fl[j];
                pa0[j] += a0 * fs;
                pa1[j] += a1 * fs;
            }
        }
        #pragma unroll
        for (int j = 0; j < 8; ++j) {
            pa0[j] += __shfl_xor(pa0[j], 32);
            pa1[j] += __shfl_xor(pa1[j], 32);
        }
        if (l < 32) {
            float* p0 = partial + (((size_t)(b*16 + c)*8 + 2*w    )*256) + ig*8;
            float* p1 = partial + (((size_t)(b*16 + c)*8 + 2*w + 1)*256) + ig*8;
            float4 v0 = {pa0[0], pa0[1], pa0[2], pa0[3]};
            float4 v1 = {pa0[4], pa0[5], pa0[6], pa0[7]};
            float4 v2 = {pa1[0], pa1[1], pa1[2], pa1[3]};
            float4 v3 = {pa1[4], pa1[5], pa1[6], pa1[7]};
            *(float4*)p0 = v0; *(float4*)(p0 + 4) = v1;
            *(float4*)p1 = v2; *(float4*)(p1 + 4) = v3;
        }
    }
}

// ---------- K5: reduce ax + updates=ax@Wv^T + GRU + LN + MLP + residual ----------
__global__ __launch_bounds__(256) void gru_mlp(const float* __restrict__ partial,
                                               const float* __restrict__ slots,
                                               const float* __restrict__ Wv,
                                               const float* __restrict__ W_ih,
                                               const float* __restrict__ W_hh,
                                               const float* __restrict__ b_ih,
                                               const float* __restrict__ b_hh,
                                               const float* __restrict__ mlp_g,
                                               const float* __restrict__ mlp_b,
                                               const float* __restrict__ W1,
                                               const float* __restrict__ b1,
                                               const float* __restrict__ W2,
                                               const float* __restrict__ b2,
                                               float* __restrict__ slots_out,
                                               float* __restrict__ out_slots,
                                               int last) {
    int rrow = blockIdx.x, t = threadIdx.x;
    int b = rrow >> 3, k = rrow & 7;
    __shared__ float ax_s[256], u_s[256], h_s[256];
    __shared__ float hn[256], m1[512];
    __shared__ float red[8];
    float axv = 0.0f;
    #pragma unroll
    for (int ch = 0; ch < 16; ++ch)
        axv += partial[(((size_t)(b*16 + ch)*8 + k)*256) + t];
    ax_s[t] = axv;
    h_s[t] = slots[rrow*256 + t];
    __syncthreads();

    // updates[d=t] = sum_i ax[i] * Wv[t, i]
    float uacc = 0.0f;
    {
        const float4* wv = (const float4*)(Wv + (size_t)t*256);
        #pragma unroll 8
        for (int i = 0; i < 64; ++i) {
            float4 ww = wv[i];
            uacc += ww.x*ax_s[4*i] + ww.y*ax_s[4*i+1] + ww.z*ax_s[4*i+2] + ww.w*ax_s[4*i+3];
        }
    }
    u_s[t] = uacc;
    __syncthreads();

    float gi_r = b_ih[t], gi_z = b_ih[256 + t], gi_n = b_ih[512 + t];
    float gh_r = b_hh[t], gh_z = b_hh[256 + t], gh_n = b_hh[512 + t];
    const float4* wir = (const float4*)(W_ih + (size_t)t*256);
    const float4* wiz = (const float4*)(W_ih + (size_t)(256 + t)*256);
    const float4* win = (const float4*)(W_ih + (size_t)(512 + t)*256);
    const float4* whr = (const float4*)(W_hh + (size_t)t*256);
    const float4* whz = (const float4*)(W_hh + (size_t)(256 + t)*256);
    const float4* whn = (const float4*)(W_hh + (size_t)(512 + t)*256);
    #pragma unroll 4
    for (int i = 0; i < 64; ++i) {
        float u0 = u_s[4*i], u1 = u_s[4*i+1], u2 = u_s[4*i+2], u3 = u_s[4*i+3];
        float h0 = h_s[4*i], h1 = h_s[4*i+1], h2 = h_s[4*i+2], h3 = h_s[4*i+3];
        float4 wv;
        wv = wir[i]; gi_r += wv.x*u0 + wv.y*u1 + wv.z*u2 + wv.w*u3;
        wv = wiz[i]; gi_z += wv.x*u0 + wv.y*u1 + wv.z*u2 + wv.w*u3;
        wv = win[i]; gi_n += wv.x*u0 + wv.y*u1 + wv.z*u2 + wv.w*u3;
        wv = whr[i]; gh_r += wv.x*h0 + wv.y*h1 + wv.z*h2 + wv.w*h3;
        wv = whz[i]; gh_z += wv.x*h0 + wv.y*h1 + wv.z*h2 + wv.w*h3;
        wv = whn[i]; gh_n += wv.x*h0 + wv.y*h1 + wv.z*h2 + wv.w*h3;
    }
    float rg = sigmoidf_(gi_r + gh_r);
    float zg = sigmoidf_(gi_z + gh_z);
    float ng = tanhf(gi_n + rg * gh_n);
    float hval = (1.0f - zg)*ng + zg*h_s[t];

    // LN(hval)
    float s = hval, s2 = hval*hval;
    for (int off = 32; off > 0; off >>= 1) {
        s  += __shfl_down(s, off);
        s2 += __shfl_down(s2, off);
    }
    __syncthreads();
    if ((t & 63) == 0) { red[t>>6] = s; red[4 + (t>>6)] = s2; }
    __syncthreads();
    float S  = red[0]+red[1]+red[2]+red[3];
    float S2 = red[4]+red[5]+red[6]+red[7];
    float m = S * (1.0f/256.0f);
    float var = S2 * (1.0f/256.0f) - m*m;
    float rs = rsqrtf(var + LN_EPS);
    hn[t] = (hval - m) * rs * mlp_g[t] + mlp_b[t];
    __syncthreads();

    #pragma unroll
    for (int jj = 0; jj < 2; ++jj) {
        int j = t + jj*256;
        float acc = b1[j];
        const float4* wv = (const float4*)(W1 + (size_t)j*256);
        #pragma unroll 8
        for (int i = 0; i < 64; ++i) {
            float4 ww = wv[i];
            acc += ww.x*hn[4*i] + ww.y*hn[4*i+1] + ww.z*hn[4*i+2] + ww.w*hn[4*i+3];
        }
        m1[j] = 0.5f * acc * (1.0f + erff(acc * 0.70710678118654752f));
    }
    __syncthreads();

    float acc = b2[t];
    const float4* w2 = (const float4*)(W2 + (size_t)t*512);
    #pragma unroll 8
    for (int i = 0; i < 128; ++i) {
        float4 ww = w2[i];
        acc += ww.x*m1[4*i] + ww.y*m1[4*i+1] + ww.z*m1[4*i+2] + ww.w*m1[4*i+3];
    }
    float res = hval + acc;
    slots_out[rrow*256 + t] = res;
    if (last) out_slots[rrow*256 + t] = res;
}

// ---------- launch ----------
extern "C" void kernel_launch(void* const* d_in, const int* in_sizes, int n_in,
                              void* d_out, int out_size, void* d_ws, size_t ws_size,
                              hipStream_t stream) {
    const float* x        = (const float*)d_in[0];
    const float* noise    = (const float*)d_in[1];
    const float* nx_g     = (const float*)d_in[2];
    const float* nx_b     = (const float*)d_in[3];
    const float* ns_g     = (const float*)d_in[4];
    const float* ns_b     = (const float*)d_in[5];
    const float* mu       = (const float*)d_in[6];
    const float* logsigma = (const float*)d_in[7];
    const float* Wq       = (const float*)d_in[8];
    const float* Wk       = (const float*)d_in[9];
    const float* Wv       = (const float*)d_in[10];
    const float* W_ih     = (const float*)d_in[11];
    const float* W_hh     = (const float*)d_in[12];
    const float* b_ih     = (const float*)d_in[13];
    const float* b_hh     = (const float*)d_in[14];
    const float* mlp_g    = (const float*)d_in[15];
    const float* mlp_b    = (const float*)d_in[16];
    const float* W1       = (const float*)d_in[17];
    const float* b1       = (const float*)d_in[18];
    const float* W2       = (const float*)d_in[19];
    const float* b2       = (const float*)d_in[20];

    float* out_slots = (float*)d_out;            // [32][8][256]
    float* out_attn  = (float*)d_out + 65536;    // [32][8][4096]

    char* ws = (char*)d_ws;
    unsigned short* xnh = (unsigned short*)ws;                   // 67 MB
    unsigned short* xnl = xnh + (size_t)33554432;                // 67 MB
    unsigned short* qkb = xnl + (size_t)33554432;                // 256 KB
    float* slots  = (float*)(qkb + 131072);                      // 256 KB
    float* partial= slots + 65536;                               // 4 MB

    xn_pass<<<2048, 256, 0, stream>>>(x, nx_g, nx_b, xnh, xnl);
    slots_init<<<256, 256, 0, stream>>>(noise, mu, logsigma, slots);

    for (int it = 0; it < 3; ++it) {
        qkproj<<<256, 256, 0, stream>>>(slots, ns_g, ns_b, Wq, Wk, qkb);
        attn_fused<<<512, 256, 0, stream>>>(xnh, xnl, qkb, out_attn, partial);
        gru_mlp<<<256, 256, 0, stream>>>(partial, slots, Wv, W_ih, W_hh, b_ih, b_hh,
                                         mlp_g, mlp_b, W1, b1, W2, b2,
                                         slots, out_slots, it == 2);
    }
}

// Round 8
// 847.368 us; speedup vs baseline: 1.0629x; 1.0629x over previous
//
#include <hip/hip_runtime.h>
#include <hip/hip_bf16.h>
#include <math.h>

#define LN_EPS 1e-5f
#define EPSA 1e-8f
#define SCALE 0.0625f   // 256^-0.5

typedef __attribute__((ext_vector_type(8))) short short8;
typedef __attribute__((ext_vector_type(4))) float f32x4;

__device__ inline unsigned short f2bf(float f) {
    union { float f; unsigned int u; } v; v.f = f;
    unsigned int r = v.u + 0x7fffu + ((v.u >> 16) & 1u);   // RNE
    return (unsigned short)(r >> 16);
}
__device__ inline float bf2f(unsigned short h) {
    union { unsigned int u; float f; } v; v.u = ((unsigned int)h) << 16;
    return v.f;
}
__device__ inline float sigmoidf_(float x) { return 1.0f / (1.0f + expf(-x)); }

// ---------- P1: Wqk = Wq^T @ Wk  [256 d][256 t] ----------
__global__ __launch_bounds__(256) void wqk_prep(const float* __restrict__ Wq,
                                                const float* __restrict__ Wk,
                                                float* __restrict__ Wqk) {
    __shared__ float wq[256][8];
    const int t = threadIdx.x;
    const int d0 = blockIdx.x * 8;
    // stage Wq[:, d0..d0+7]: thread t reads Wq[t][d0..+7]
    float4 a = *(const float4*)(Wq + (size_t)t*256 + d0);
    float4 b = *(const float4*)(Wq + (size_t)t*256 + d0 + 4);
    wq[t][0]=a.x; wq[t][1]=a.y; wq[t][2]=a.z; wq[t][3]=a.w;
    wq[t][4]=b.x; wq[t][5]=b.y; wq[t][6]=b.z; wq[t][7]=b.w;
    __syncthreads();
    float acc[8] = {0,0,0,0,0,0,0,0};
    for (int i = 0; i < 256; ++i) {
        float wk = Wk[(size_t)i*256 + t];
        #pragma unroll
        for (int j = 0; j < 8; ++j) acc[j] += wq[i][j] * wk;
    }
    #pragma unroll
    for (int j = 0; j < 8; ++j) Wqk[(size_t)(d0 + j)*256 + t] = acc[j];
}

// ---------- P2: batched 64x64 tile transpose of the 5 weight matrices ----------
__global__ __launch_bounds__(256) void wtrans(const float* __restrict__ Wv,
                                              const float* __restrict__ W_ih,
                                              const float* __restrict__ W_hh,
                                              const float* __restrict__ W1,
                                              const float* __restrict__ W2,
                                              float* __restrict__ WvT,
                                              float* __restrict__ WihT,
                                              float* __restrict__ WhhT,
                                              float* __restrict__ W1T,
                                              float* __restrict__ W2T) {
    __shared__ float tile[64][65];
    const int t = threadIdx.x;
    int id = blockIdx.x;
    const float* in; float* out; int O, K, base;
    if      (id < 16)  { in = Wv;   out = WvT;  O = 256; K = 256; base = 0;   }
    else if (id < 64)  { in = W_ih; out = WihT; O = 768; K = 256; base = 16;  }
    else if (id < 112) { in = W_hh; out = WhhT; O = 768; K = 256; base = 64;  }
    else if (id < 144) { in = W1;   out = W1T;  O = 512; K = 256; base = 112; }
    else               { in = W2;   out = W2T;  O = 256; K = 512; base = 144; }
    int local = id - base;
    int tiles_o = O >> 6;
    int o0 = (local % tiles_o) * 64;
    int k0 = (local / tiles_o) * 64;
    #pragma unroll
    for (int jj = 0; jj < 16; ++jj) {
        int flat = jj*256 + t;
        int i = flat >> 6, j = flat & 63;
        tile[i][j] = in[(size_t)(o0 + i)*K + k0 + j];
    }
    __syncthreads();
    #pragma unroll
    for (int jj = 0; jj < 16; ++jj) {
        int flat = jj*256 + t;
        int jp = flat >> 6, ip = flat & 63;
        out[(size_t)(k0 + jp)*O + o0 + ip] = tile[ip][jp];
    }
}

// ---------- K1: slots init ----------
__global__ __launch_bounds__(256) void slots_init(const float* __restrict__ noise,
                                                  const float* __restrict__ mu,
                                                  const float* __restrict__ logsigma,
                                                  float* __restrict__ slots) {
    int i = blockIdx.x * 256 + threadIdx.x;   // 65536
    int d = i & 255;
    slots[i] = mu[d] + expf(logsigma[d]) * noise[i];
}

// ---------- K2: LN(slots) + qk = sn @ Wqk, hi/lo bf16 out -> qkb[b][16][256] ----------
__global__ __launch_bounds__(256) void qkproj(const float* __restrict__ slots,
                                              const float* __restrict__ ns_g,
                                              const float* __restrict__ ns_b,
                                              const float* __restrict__ Wqk,
                                              unsigned short* __restrict__ qkb) {
    __shared__ float sl[8][256];
    const int b = blockIdx.x, t = threadIdx.x;
    #pragma unroll
    for (int s = 0; s < 8; ++s)
        sl[s][t] = slots[((size_t)(b*8 + s))*256 + t];
    __syncthreads();
    // group m = t>>5 handles row m; lane c = t&31 covers cols c+32j
    const int m = t >> 5, c = t & 31;
    float v[8];
    float s1 = 0.f, s2 = 0.f;
    #pragma unroll
    for (int j = 0; j < 8; ++j) {
        v[j] = sl[m][c + 32*j];
        s1 += v[j]; s2 += v[j]*v[j];
    }
    s1 += __shfl_xor(s1, 1);  s2 += __shfl_xor(s2, 1);
    s1 += __shfl_xor(s1, 2);  s2 += __shfl_xor(s2, 2);
    s1 += __shfl_xor(s1, 4);  s2 += __shfl_xor(s2, 4);
    s1 += __shfl_xor(s1, 8);  s2 += __shfl_xor(s2, 8);
    s1 += __shfl_xor(s1, 16); s2 += __shfl_xor(s2, 16);
    float mean = s1 * (1.0f/256.0f);
    float var  = s2 * (1.0f/256.0f) - mean*mean;
    float rstd = rsqrtf(var + LN_EPS);
    #pragma unroll
    for (int j = 0; j < 8; ++j) {
        int col = c + 32*j;
        sl[m][col] = (v[j] - mean) * rstd * ns_g[col] + ns_b[col];
    }
    __syncthreads();
    float acc[8] = {0,0,0,0,0,0,0,0};
    for (int d = 0; d < 256; ++d) {
        float w = Wqk[(size_t)d*256 + t];
        #pragma unroll
        for (int s = 0; s < 8; ++s) acc[s] += sl[s][d] * w;
    }
    #pragma unroll
    for (int s = 0; s < 8; ++s) {
        unsigned short hh = f2bf(acc[s]);
        unsigned short ll = f2bf(acc[s] - bf2f(hh));
        qkb[((size_t)(b*16 + s))*256 + t]     = hh;
        qkb[((size_t)(b*16 + 8 + s))*256 + t] = ll;
    }
}

// ---------- K3: LDS-fused attn: stage x chunk, LN inline, MFMA logits (hi/lo),
//                softmax, attn out, f32 VALU ax; x read once per iter ----------
__global__ __launch_bounds__(256) void attn_fused(const float* __restrict__ x,
                                                  const float* __restrict__ nx_g,
                                                  const float* __restrict__ nx_b,
                                                  const unsigned short* __restrict__ qkb,
                                                  float* __restrict__ attn_out,
                                                  float* __restrict__ partial) {
    __shared__ unsigned short xh[32*264];   // MFMA-A hi, stride 264 (pad, conflict-free)
    __shared__ unsigned short xl[32*264];   // MFMA-A lo
    __shared__ float xf[32*257];            // f32 for ax
    __shared__ float lgP[2*32*8];           // [part][n][slot]
    __shared__ float asf[8*32];             // [slot][n]
    const int b = blockIdx.x >> 4, c = blockIdx.x & 15;
    const int t = threadIdx.x, l = t & 63, w = t >> 6;
    const int lr = l & 15, lk = l >> 4;
    const int tile = w & 1, part = w >> 1;
    const int m = t >> 5;                   // staging row-group: rows m, m+8, m+16, m+24
    const int dcol = (t & 31) * 8;          // this thread's fixed d-window
    const size_t xbase = ((size_t)b*4096 + (size_t)c*256) * 256;

    // fixed LN params for dcol window
    float4 g0 = *(const float4*)(nx_g + dcol);
    float4 g1 = *(const float4*)(nx_g + dcol + 4);
    float4 bb0 = *(const float4*)(nx_b + dcol);
    float4 bb1 = *(const float4*)(nx_b + dcol + 4);

    // qk fragments (B-rows 0-7 = hi slots, 8-15 = lo slots)
    short8 qf[8];
    #pragma unroll
    for (int ks = 0; ks < 8; ++ks)
        qf[ks] = *(const short8*)(qkb + ((size_t)(b*16 + lr))*256 + ks*32 + lk*8);

    float4 sx[4][2];   // staged x: [j][half] for rows m+8j

    float pacc[8] = {0,0,0,0,0,0,0,0};   // ax accumulator: slot t>>5, d = dcol..+7
    const int axs = t >> 5;

    // ---- staging helpers (inline via macros to keep registers) ----
    #define STAGE_LOAD(CH) {                                              \
        _Pragma("unroll")                                                 \
        for (int j = 0; j < 4; ++j) {                                     \
            int row = m + 8*j;                                            \
            const float* src = x + xbase + (size_t)((CH)*32 + row)*256 + dcol; \
            sx[j][0] = *(const float4*)src;                               \
            sx[j][1] = *(const float4*)(src + 4);                         \
        } }

    #define STAGE_WRITE() {                                               \
        _Pragma("unroll")                                                 \
        for (int j = 0; j < 4; ++j) {                                     \
            float e[8] = { sx[j][0].x, sx[j][0].y, sx[j][0].z, sx[j][0].w,\
                           sx[j][1].x, sx[j][1].y, sx[j][1].z, sx[j][1].w };\
            float s1 = 0.f, s2 = 0.f;                                     \
            _Pragma("unroll")                                             \
            for (int q = 0; q < 8; ++q) { s1 += e[q]; s2 += e[q]*e[q]; }  \
            s1 += __shfl_xor(s1, 1);  s2 += __shfl_xor(s2, 1);            \
            s1 += __shfl_xor(s1, 2);  s2 += __shfl_xor(s2, 2);            \
            s1 += __shfl_xor(s1, 4);  s2 += __shfl_xor(s2, 4);            \
            s1 += __shfl_xor(s1, 8);  s2 += __shfl_xor(s2, 8);            \
            s1 += __shfl_xor(s1, 16); s2 += __shfl_xor(s2, 16);           \
            float mean = s1 * (1.0f/256.0f);                              \
            float var  = s2 * (1.0f/256.0f) - mean*mean;                  \
            float rstd = rsqrtf(var + LN_EPS);                            \
            e[0] = (e[0]-mean)*rstd*g0.x + bb0.x;                         \
            e[1] = (e[1]-mean)*rstd*g0.y + bb0.y;                         \
            e[2] = (e[2]-mean)*rstd*g0.z + bb0.z;                         \
            e[3] = (e[3]-mean)*rstd*g0.w + bb0.w;                         \
            e[4] = (e[4]-mean)*rstd*g1.x + bb1.x;                         \
            e[5] = (e[5]-mean)*rstd*g1.y + bb1.y;                         \
            e[6] = (e[6]-mean)*rstd*g1.z + bb1.z;                         \
            e[7] = (e[7]-mean)*rstd*g1.w + bb1.w;                         \
            int row = m + 8*j;                                            \
            short8 hh, ll;                                                \
            _Pragma("unroll")                                             \
            for (int q = 0; q < 8; ++q) {                                 \
                unsigned short hv = f2bf(e[q]);                           \
                hh[q] = (short)hv;                                        \
                ll[q] = (short)f2bf(e[q] - bf2f(hv));                     \
            }                                                             \
            *(short8*)((char*)xh + (size_t)row*528 + (size_t)dcol*2) = hh;\
            *(short8*)((char*)xl + (size_t)row*528 + (size_t)dcol*2) = ll;\
            *(float4*)(xf + row*257 + dcol)     = (float4){e[0],e[1],e[2],e[3]};\
            *(float4*)(xf + row*257 + dcol + 4) = (float4){e[4],e[5],e[6],e[7]};\
        } }

    STAGE_LOAD(0);
    STAGE_WRITE();
    __syncthreads();

    const float renorm = 1.0f / (1.0f + 8.0f*EPSA);
    for (int chunk = 0; chunk < 8; ++chunk) {
        if (chunk < 7) STAGE_LOAD(chunk + 1);

        // MFMA logits: this wave: A = (part?lo:hi), rows tile*16..+15
        {
            const unsigned short* xa = part ? xl : xh;
            f32x4 acc = (f32x4){0.f,0.f,0.f,0.f};
            #pragma unroll
            for (int ks = 0; ks < 8; ++ks) {
                short8 a = *(const short8*)((const char*)xa +
                    (size_t)(tile*16 + lr)*528 + (size_t)(ks*32 + lk*8)*2);
                acc = __builtin_amdgcn_mfma_f32_16x16x32_bf16(a, qf[ks], acc, 0, 0, 0);
            }
            #pragma unroll
            for (int jj = 0; jj < 4; ++jj) {
                float v = acc[jj];
                v += __shfl_xor(v, 8);    // col s + col s+8 (qk hi + lo)
                if (!(l & 8))
                    lgP[part*256 + (tile*16 + (l>>4)*4 + jj)*8 + (l & 7)] = v;
            }
        }
        __syncthreads();

        // softmax over 8 slots per n (threads 0-31)
        if (t < 32) {
            int n = t;
            float lg[8], mx = -1e30f;
            #pragma unroll
            for (int s = 0; s < 8; ++s) {
                lg[s] = (lgP[n*8 + s] + lgP[256 + n*8 + s]) * SCALE;
                mx = fmaxf(mx, lg[s]);
            }
            float ssum = 0.f;
            #pragma unroll
            for (int s = 0; s < 8; ++s) { lg[s] = expf(lg[s] - mx); ssum += lg[s]; }
            float inv = 1.0f / ssum;
            #pragma unroll
            for (int s = 0; s < 8; ++s)
                asf[s*32 + n] = (lg[s]*inv + EPSA) * renorm;
        }
        __syncthreads();

        // attn output (coalesced) + ax accumulate
        {
            int s = t >> 5, n = t & 31;
            attn_out[((size_t)(b*8 + s))*4096 + c*256 + chunk*32 + n] = asf[s*32 + n];
        }
        {
            const float* arow = &asf[axs*32];
            #pragma unroll 4
            for (int n = 0; n < 32; ++n) {
                float a = arow[n];
                float4 v0 = *(const float4*)(xf + n*257 + dcol);
                float4 v1 = *(const float4*)(xf + n*257 + dcol + 4);
                pacc[0] += a*v0.x; pacc[1] += a*v0.y; pacc[2] += a*v0.z; pacc[3] += a*v0.w;
                pacc[4] += a*v1.x; pacc[5] += a*v1.y; pacc[6] += a*v1.z; pacc[7] += a*v1.w;
            }
        }
        __syncthreads();

        if (chunk < 7) {
            STAGE_WRITE();
            __syncthreads();
        }
    }

    float* p = partial + (((size_t)(b*16 + c)*8 + axs))*256 + dcol;
    *(float4*)p       = (float4){pacc[0], pacc[1], pacc[2], pacc[3]};
    *(float4*)(p + 4) = (float4){pacc[4], pacc[5], pacc[6], pacc[7]};
    #undef STAGE_LOAD
    #undef STAGE_WRITE
}

// ---------- K4: reduce ax + updates + GRU + LN + MLP + residual (4 rows/block) ----------
__global__ __launch_bounds__(256) void gru_mlp(const float* __restrict__ partial,
                                               const float* __restrict__ slots,
                                               const float* __restrict__ WvT,
                                               const float* __restrict__ WihT,
                                               const float* __restrict__ WhhT,
                                               const float* __restrict__ b_ih,
                                               const float* __restrict__ b_hh,
                                               const float* __restrict__ mlp_g,
                                               const float* __restrict__ mlp_b,
                                               const float* __restrict__ W1T,
                                               const float* __restrict__ b1,
                                               const float* __restrict__ W2T,
                                               const float* __restrict__ b2,
                                               float* __restrict__ slots_out,
                                               float* __restrict__ out_slots,
                                               int last) {
    __shared__ float ax_s[4][256], u_s[4][256], h_s[4][256];
    __shared__ float hn[4][256], m1s[4][512];
    __shared__ float redS[4][4], redS2[4][4];
    const int t = threadIdx.x, l = t & 63, w = t >> 6;
    const int r0 = blockIdx.x * 4;            // 4 slot-rows, same batch b
    const int b = r0 >> 3;

    #pragma unroll
    for (int i = 0; i < 4; ++i) {
        int k = (r0 + i) & 7;
        float a = 0.f;
        #pragma unroll
        for (int ch = 0; ch < 16; ++ch)
            a += partial[(((size_t)(b*16 + ch)*8 + k))*256 + t];
        ax_s[i][t] = a;
        h_s[i][t] = slots[(size_t)(r0 + i)*256 + t];
    }
    __syncthreads();

    // updates: u[i][t] = sum_d ax[i][d] * WvT[d][t]
    {
        float acc[4] = {0,0,0,0};
        for (int d = 0; d < 256; ++d) {
            float wv = WvT[(size_t)d*256 + t];
            #pragma unroll
            for (int i = 0; i < 4; ++i) acc[i] += ax_s[i][d] * wv;
        }
        #pragma unroll
        for (int i = 0; i < 4; ++i) u_s[i][t] = acc[i];
    }
    __syncthreads();

    // GRU gates
    float hval[4];
    {
        float air[4] = {0,0,0,0}, aiz[4] = {0,0,0,0}, ain[4] = {0,0,0,0};
        float ahr[4] = {0,0,0,0}, ahz[4] = {0,0,0,0}, ahn[4] = {0,0,0,0};
        for (int d = 0; d < 256; ++d) {
            float wir = WihT[(size_t)d*768 + t];
            float wiz = WihT[(size_t)d*768 + 256 + t];
            float win = WihT[(size_t)d*768 + 512 + t];
            float whr = WhhT[(size_t)d*768 + t];
            float whz = WhhT[(size_t)d*768 + 256 + t];
            float whn = WhhT[(size_t)d*768 + 512 + t];
            #pragma unroll
            for (int i = 0; i < 4; ++i) {
                float u = u_s[i][d], h = h_s[i][d];
                air[i] += u*wir; aiz[i] += u*wiz; ain[i] += u*win;
                ahr[i] += h*whr; ahz[i] += h*whz; ahn[i] += h*whn;
            }
        }
        float bir = b_ih[t], biz = b_ih[256 + t], bin = b_ih[512 + t];
        float bhr = b_hh[t], bhz = b_hh[256 + t], bhn = b_hh[512 + t];
        #pragma unroll
        for (int i = 0; i < 4; ++i) {
            float rg = sigmoidf_(air[i] + bir + ahr[i] + bhr);
            float zg = sigmoidf_(aiz[i] + biz + ahz[i] + bhz);
            float ng = tanhf(ain[i] + bin + rg * (ahn[i] + bhn));
            hval[i] = (1.0f - zg)*ng + zg*h_s[i][t];
        }
    }

    // LN per row (block-wide)
    {
        float s1[4], s2[4];
        #pragma unroll
        for (int i = 0; i < 4; ++i) { s1[i] = hval[i]; s2[i] = hval[i]*hval[i]; }
        #pragma unroll
        for (int off = 1; off < 64; off <<= 1) {
            #pragma unroll
            for (int i = 0; i < 4; ++i) {
                s1[i] += __shfl_xor(s1[i], off);
                s2[i] += __shfl_xor(s2[i], off);
            }
        }
        if (l == 0) {
            #pragma unroll
            for (int i = 0; i < 4; ++i) { redS[w][i] = s1[i]; redS2[w][i] = s2[i]; }
        }
        __syncthreads();
        #pragma unroll
        for (int i = 0; i < 4; ++i) {
            float S  = redS[0][i] + redS[1][i] + redS[2][i] + redS[3][i];
            float S2 = redS2[0][i] + redS2[1][i] + redS2[2][i] + redS2[3][i];
            float mean = S * (1.0f/256.0f);
            float var  = S2 * (1.0f/256.0f) - mean*mean;
            float rstd = rsqrtf(var + LN_EPS);
            hn[i][t] = (hval[i] - mean) * rstd * mlp_g[t] + mlp_b[t];
        }
    }
    __syncthreads();

    // MLP layer 1 + GELU: cols t and t+256
    {
        float acc0[4], acc1[4];
        float bb0 = b1[t], bb1 = b1[256 + t];
        #pragma unroll
        for (int i = 0; i < 4; ++i) { acc0[i] = bb0; acc1[i] = bb1; }
        for (int d = 0; d < 256; ++d) {
            float wa = W1T[(size_t)d*512 + t];
            float wb = W1T[(size_t)d*512 + 256 + t];
            #pragma unroll
            for (int i = 0; i < 4; ++i) {
                float h = hn[i][d];
                acc0[i] += h*wa; acc1[i] += h*wb;
            }
        }
        #pragma unroll
        for (int i = 0; i < 4; ++i) {
            m1s[i][t]       = 0.5f*acc0[i]*(1.0f + erff(acc0[i]*0.70710678118654752f));
            m1s[i][t + 256] = 0.5f*acc1[i]*(1.0f + erff(acc1[i]*0.70710678118654752f));
        }
    }
    __syncthreads();

    // MLP layer 2 + residual
    {
        float acc[4];
        float bb = b2[t];
        #pragma unroll
        for (int i = 0; i < 4; ++i) acc[i] = bb;
        for (int d = 0; d < 512; ++d) {
            float w2 = W2T[(size_t)d*256 + t];
            #pragma unroll
            for (int i = 0; i < 4; ++i) acc[i] += m1s[i][d] * w2;
        }
        #pragma unroll
        for (int i = 0; i < 4; ++i) {
            float res = hval[i] + acc[i];
            slots_out[(size_t)(r0 + i)*256 + t] = res;
            if (last) out_slots[(size_t)(r0 + i)*256 + t] = res;
        }
    }
}

// ---------- launch ----------
extern "C" void kernel_launch(void* const* d_in, const int* in_sizes, int n_in,
                              void* d_out, int out_size, void* d_ws, size_t ws_size,
                              hipStream_t stream) {
    const float* x        = (const float*)d_in[0];
    const float* noise    = (const float*)d_in[1];
    const float* nx_g     = (const float*)d_in[2];
    const float* nx_b     = (const float*)d_in[3];
    const float* ns_g     = (const float*)d_in[4];
    const float* ns_b     = (const float*)d_in[5];
    const float* mu       = (const float*)d_in[6];
    const float* logsigma = (const float*)d_in[7];
    const float* Wq       = (const float*)d_in[8];
    const float* Wk       = (const float*)d_in[9];
    const float* Wv       = (const float*)d_in[10];
    const float* W_ih     = (const float*)d_in[11];
    const float* W_hh     = (const float*)d_in[12];
    const float* b_ih     = (const float*)d_in[13];
    const float* b_hh     = (const float*)d_in[14];
    const float* mlp_g    = (const float*)d_in[15];
    const float* mlp_b    = (const float*)d_in[16];
    const float* W1       = (const float*)d_in[17];
    const float* b1       = (const float*)d_in[18];
    const float* W2       = (const float*)d_in[19];
    const float* b2       = (const float*)d_in[20];

    float* out_slots = (float*)d_out;            // [32][8][256]
    float* out_attn  = (float*)d_out + 65536;    // [32][8][4096]

    float* ws = (float*)d_ws;
    float* Wqk   = ws;                    // 65536
    float* WvT   = Wqk   + 65536;         // 65536
    float* WihT  = WvT   + 65536;         // 196608
    float* WhhT  = WihT  + 196608;        // 196608
    float* W1T   = WhhT  + 196608;        // 131072
    float* W2T   = W1T   + 131072;        // 131072
    unsigned short* qkb = (unsigned short*)(W2T + 131072);   // 131072 ushort
    float* slots   = (float*)(qkb + 131072);                 // 65536
    float* partial = slots + 65536;                          // 1048576

    wqk_prep<<<32, 256, 0, stream>>>(Wq, Wk, Wqk);
    wtrans<<<176, 256, 0, stream>>>(Wv, W_ih, W_hh, W1, W2, WvT, WihT, WhhT, W1T, W2T);
    slots_init<<<256, 256, 0, stream>>>(noise, mu, logsigma, slots);

    for (int it = 0; it < 3; ++it) {
        qkproj<<<32, 256, 0, stream>>>(slots, ns_g, ns_b, Wqk, qkb);
        attn_fused<<<512, 256, 0, stream>>>(x, nx_g, nx_b, qkb, out_attn, partial);
        gru_mlp<<<64, 256, 0, stream>>>(partial, slots, WvT, WihT, WhhT, b_ih, b_hh,
                                        mlp_g, mlp_b, W1T, b1, W2T, b2,
                                        slots, out_slots, it == 2);
    }
}